// Round 8
// baseline (137.708 us; speedup 1.0000x reference)
//
#include <hip/hip_runtime.h>

#define BSZ 8
#define NQ 2048
#define MP 64
#define DD 1024
#define K2ALL 2048       // interleaved ushort per (b,m) row: [m2, -2*m2*p]
#define NSTEP 64         // k32 steps

typedef __bf16 bf16x8 __attribute__((ext_vector_type(8)));
typedef float f32x4 __attribute__((ext_vector_type(4)));
typedef unsigned short us8 __attribute__((ext_vector_type(8)));

union FragU { us8 u; bf16x8 b; };

__device__ __forceinline__ unsigned short f2bf(float f) {
    union { float f; unsigned int u; } v; v.f = f;
    unsigned int u = v.u;
    return (unsigned short)((u + 0x7FFFu + ((u >> 16) & 1u)) >> 16);  // RNE
}

// Pass 1 (unchanged, verified): pack proto/mask -> bf16 [m2, -2*m2*p] in MFMA
// fragment order + fp32 pterm. Flat ushort index:
//   ((((b*4+mt)*64 + s)*64) + lane)*8 + e
// mt=m>>4, s=k32-step (t>>2), lane=(t&3)*16 + (m&15).
__global__ __launch_bounds__(256) void pack_kernel(
    const float* __restrict__ proto,
    const float* __restrict__ mask,
    unsigned short* __restrict__ Pf,
    float* __restrict__ Pterm)
{
    const int row = blockIdx.x;          // b*64 + m
    const int m = row & 63;
    const int b = row >> 6;
    const int t = threadIdx.x;           // d = 4t..4t+3 -> interleaved k = 8t..8t+7

    const float4 mk = *(const float4*)(mask  + (size_t)row * DD + 4 * t);
    const float4 pr = *(const float4*)(proto + (size_t)row * DD + 4 * t);

    const float m2x = mk.x * mk.x, m2y = mk.y * mk.y,
                m2z = mk.z * mk.z, m2w = mk.w * mk.w;
    const float ax = mk.x * pr.x, ay = mk.y * pr.y,
                az = mk.z * pr.z, aw = mk.w * pr.w;
    float pacc = ax * ax + ay * ay + az * az + aw * aw;

    us8 o;
    o[0] = f2bf(m2x); o[1] = f2bf(-2.f * m2x * pr.x);
    o[2] = f2bf(m2y); o[3] = f2bf(-2.f * m2y * pr.y);
    o[4] = f2bf(m2z); o[5] = f2bf(-2.f * m2z * pr.z);
    o[6] = f2bf(m2w); o[7] = f2bf(-2.f * m2w * pr.w);

    const int mt   = m >> 4;
    const int s    = t >> 2;
    const int lane = (t & 3) * 16 + (m & 15);
    const size_t idx = ((((size_t)(b * 4 + mt)) * 64 + s) * 64 + lane) * 8;
    *(us8*)(Pf + idx) = o;

    __shared__ float red[4];
    #pragma unroll
    for (int off = 32; off > 0; off >>= 1)
        pacc += __shfl_down(pacc, off, 64);
    const int lane64 = t & 63, w = t >> 6;
    if (lane64 == 0) red[w] = pacc;
    __syncthreads();
    if (t == 0) Pterm[row] = red[0] + red[1] + red[2] + red[3];
}

// Pass 2: LDS-free, barrier-free streaming GEMM.
// 256 blocks (1/CU; bid&7 = XCD -> fixed batch, Pf slice L2-resident),
// 4 waves/block. Each wave: 16 query rows x ALL 64 m (4 MFMAs/step).
// Query read exactly once, direct global->reg in A-fragment order with
// in-register [q^2,q] repack; B from fragment-packed Pf (1 KB/load).
// Depth-8 A queue + depth-4x4 B queue; no __syncthreads anywhere.
__global__ __launch_bounds__(256, 1) void proto_main_kernel(
    const float* __restrict__ query,
    const unsigned short* __restrict__ Pf,
    const float* __restrict__ Pterm,
    const float* __restrict__ scale,
    float* __restrict__ out)
{
    const int tid  = threadIdx.x;
    const int bid  = blockIdx.x;
    const int b    = bid & 7;                    // XCD-affine batch
    const int wid  = tid >> 6;
    const int lane = tid & 63;
    const int lrow = lane & 15;
    const int quad = lane >> 4;
    const int n0   = (bid >> 3) * 64 + wid * 16; // this wave's query rows

    // A: lane reads query[n0+lrow][16*s + 4*quad .. +3] per step s
    const float* aptr = query + ((size_t)b * NQ + n0 + lrow) * DD + 4 * quad;
    // B: fragment-packed, step stride 512 ushorts, m-tile stride 64*512
    const unsigned short* bp = Pf + ((size_t)(b * 4)) * 64 * 512 + (size_t)lane * 8;

    // ---- prime queues: ~24 loads in flight per wave immediately ----
    float4 aq[8];
    #pragma unroll
    for (int i = 0; i < 8; ++i)
        aq[i] = *(const float4*)(aptr + 16 * i);

    bf16x8 bq[4][4];   // [depth][m-tile]
    #pragma unroll
    for (int s = 0; s < 4; ++s)
        #pragma unroll
        for (int mt = 0; mt < 4; ++mt)
            bq[s][mt] = *(const bf16x8*)(bp + (size_t)mt * 32768 + (size_t)s * 512);

    // epilogue scalars (hidden under the stream)
    const float sc = scale[0] * (1.0f / (float)DD);
    float pt[4];
    #pragma unroll
    for (int mt = 0; mt < 4; ++mt)
        pt[mt] = Pterm[b * MP + 16 * mt + lrow];

    f32x4 acc[4];
    acc[0] = acc[1] = acc[2] = acc[3] = (f32x4){0.f, 0.f, 0.f, 0.f};

    // ---- 64 steps: 1 A-load + repack, 4 B-loads, 4 MFMAs; queues roll ----
    for (int g = 0; g < NSTEP; g += 8) {
        #pragma unroll
        for (int j = 0; j < 8; ++j) {
            const int s = g + j;
            const float4 q = aq[s & 7];
            if (s + 8 < NSTEP)
                aq[s & 7] = *(const float4*)(aptr + 16 * (s + 8));

            FragU af;
            af.u[0] = f2bf(q.x * q.x); af.u[1] = f2bf(q.x);
            af.u[2] = f2bf(q.y * q.y); af.u[3] = f2bf(q.y);
            af.u[4] = f2bf(q.z * q.z); af.u[5] = f2bf(q.z);
            af.u[6] = f2bf(q.w * q.w); af.u[7] = f2bf(q.w);
            const bf16x8 a = af.b;

            #pragma unroll
            for (int mt = 0; mt < 4; ++mt) {
                const bf16x8 bb = bq[s & 3][mt];
                if (s + 4 < NSTEP)
                    bq[s & 3][mt] = *(const bf16x8*)(
                        bp + (size_t)mt * 32768 + (size_t)(s + 4) * 512);
                acc[mt] = __builtin_amdgcn_mfma_f32_16x16x32_bf16(a, bb, acc[mt], 0, 0, 0);
            }
        }
    }

    // ---- epilogue: n = n0 + quad*4 + r, m = 16*mt + lrow ----
    #pragma unroll
    for (int mt = 0; mt < 4; ++mt) {
        const size_t ob =
            ((size_t)b * NQ + (size_t)(n0 + quad * 4)) * MP + 16 * mt + lrow;
        #pragma unroll
        for (int r = 0; r < 4; ++r)
            out[ob + (size_t)r * MP] = (acc[mt][r] + pt[mt]) * sc;
    }
}

extern "C" void kernel_launch(void* const* d_in, const int* in_sizes, int n_in,
                              void* d_out, int out_size, void* d_ws, size_t ws_size,
                              hipStream_t stream) {
    (void)in_sizes; (void)n_in; (void)ws_size; (void)out_size;
    const float* proto = (const float*)d_in[0];
    const float* mask  = (const float*)d_in[1];
    const float* query = (const float*)d_in[2];
    const float* scale = (const float*)d_in[5];
    float* out = (float*)d_out;

    unsigned short* Pf = (unsigned short*)d_ws;                           // 2 MiB
    float* Pterm = (float*)((char*)d_ws + (size_t)BSZ * MP * K2ALL * 2);  // +2 KiB

    pack_kernel<<<dim3(BSZ * MP), dim3(256), 0, stream>>>(proto, mask, Pf, Pterm);
    proto_main_kernel<<<dim3(256), dim3(256), 0, stream>>>(
        query, Pf, Pterm, scale, out);
}

// Round 9
// 136.280 us; speedup vs baseline: 1.0105x; 1.0105x over previous
//
#include <hip/hip_runtime.h>
#include <hip/hip_bf16.h>

#define BSZ 8
#define NQ 2048
#define MP 64
#define DD 1024
#define K2ALL 2048       // interleaved ushort per (b,m) row: [m2, -2*m2*p]
#define BN 32            // query rows per block
#define BK 64            // d per chunk
#define KT 16            // DD / BK
#define NTILES (NQ / BN) // 64 -> grid 512 = 2 blocks/CU

typedef __bf16 bf16x8 __attribute__((ext_vector_type(8)));
typedef float f32x4 __attribute__((ext_vector_type(4)));
typedef unsigned short us8 __attribute__((ext_vector_type(8)));

__device__ __forceinline__ unsigned short f2bf(float f) {
    union { float f; unsigned int u; } v; v.f = f;
    unsigned int u = v.u;
    return (unsigned short)((u + 0x7FFFu + ((u >> 16) & 1u)) >> 16);  // RNE
}

// async 16B/lane global->LDS DMA. LDS dest = uniform base + lane*16 (HW rule).
__device__ __forceinline__ void async_ld16(const void* g, void* l) {
    __builtin_amdgcn_global_load_lds(
        (const __attribute__((address_space(1))) unsigned int*)g,
        (__attribute__((address_space(3))) unsigned int*)l, 16, 0, 0);
}

// packed (lo=a, hi=b) bf16 pair via v_cvt_pk_bf16_f32 (RNE)
__device__ __forceinline__ unsigned int pk2(float a, float b) {
    union { __hip_bfloat162 h; unsigned int u; } c;
    c.h = __float22bfloat162_rn(make_float2(a, b));
    return c.u;
}

// Pass 1 (verified R4-R8): pack proto/mask -> bf16 [m2, -2*m2*p] in MFMA
// fragment order + fp32 pterm. Flat ushort index:
//   ((((b*4+mt)*64 + s)*64) + lane)*8 + e
// mt=m>>4, s=k32-step (t>>2), lane=(t&3)*16 + (m&15).
__global__ __launch_bounds__(256) void pack_kernel(
    const float* __restrict__ proto,
    const float* __restrict__ mask,
    unsigned short* __restrict__ Pf,
    float* __restrict__ Pterm)
{
    const int row = blockIdx.x;          // b*64 + m
    const int m = row & 63;
    const int b = row >> 6;
    const int t = threadIdx.x;           // d = 4t..4t+3 -> interleaved k = 8t..8t+7

    const float4 mk = *(const float4*)(mask  + (size_t)row * DD + 4 * t);
    const float4 pr = *(const float4*)(proto + (size_t)row * DD + 4 * t);

    const float m2x = mk.x * mk.x, m2y = mk.y * mk.y,
                m2z = mk.z * mk.z, m2w = mk.w * mk.w;
    const float ax = mk.x * pr.x, ay = mk.y * pr.y,
                az = mk.z * pr.z, aw = mk.w * pr.w;
    float pacc = ax * ax + ay * ay + az * az + aw * aw;

    us8 o;
    o[0] = f2bf(m2x); o[1] = f2bf(-2.f * m2x * pr.x);
    o[2] = f2bf(m2y); o[3] = f2bf(-2.f * m2y * pr.y);
    o[4] = f2bf(m2z); o[5] = f2bf(-2.f * m2z * pr.z);
    o[6] = f2bf(m2w); o[7] = f2bf(-2.f * m2w * pr.w);

    const int mt   = m >> 4;
    const int s    = t >> 2;
    const int lane = (t & 3) * 16 + (m & 15);
    const size_t idx = ((((size_t)(b * 4 + mt)) * 64 + s) * 64 + lane) * 8;
    *(us8*)(Pf + idx) = o;

    __shared__ float red[4];
    #pragma unroll
    for (int off = 32; off > 0; off >>= 1)
        pacc += __shfl_down(pacc, off, 64);
    const int lane64 = t & 63, w = t >> 6;
    if (lane64 == 0) red[w] = pacc;
    __syncthreads();
    if (t == 0) Pterm[row] = red[0] + red[1] + red[2] + red[3];
}

// Pass 2: m97-style async-DMA GEMM. 512 blocks (b=bid&7 XCD-affine), 4 waves.
// Tile 32n x 64m, BK=64, dbuf LDS staged ONLY via global_load_lds (no VGPR
// queues for the compiler to collapse). One barrier per chunk:
//   bar -> issue stage(kt+1) -> compute(kt).
// A staged raw fp32, XOR-swizzled: slot(row,dg) = row*16 + (dg ^ (row&15)),
// dg = d/4. Stager covers slot seg*64+lane; reader frag(sl,quad) reads
// slot row*16 + ((4sl+quad)^lrow) -> 2-way bank conflicts only.
// B staged in Pf fragment order (lane-contiguous by construction).
__global__ __launch_bounds__(256, 2) void proto_main_kernel(
    const float* __restrict__ query,
    const unsigned short* __restrict__ Pf,
    const float* __restrict__ Pterm,
    const float* __restrict__ scale,
    float* __restrict__ out)
{
    __shared__ float          Qsh[2][BN * BK];   // 2 x 8 KB raw fp32 (swizzled)
    __shared__ unsigned short Bsh[2][16 * 512];  // 2 x 16 KB fragment-order

    const int tid = threadIdx.x;
    const int bid = blockIdx.x;
    const int b   = bid & 7;
    const int n0  = (bid >> 3) * BN;

    const int lane = tid & 63;
    const int wid  = tid >> 6;
    const int lrow = lane & 15;
    const int quad = lane >> 4;

    // ---- A staging source (per-lane): seg = wid*2+i, row = seg*4 + (lane>>4),
    //      dg = (lane&15) ^ (row&15); lands at LDS slot seg*64+lane. ----
    const int row0 = (wid * 2 + 0) * 4 + quad;
    const int row1 = (wid * 2 + 1) * 4 + quad;
    const float* qsrc0 = query + ((size_t)b * NQ + n0 + row0) * DD + 4 * (lrow ^ (row0 & 15));
    const float* qsrc1 = query + ((size_t)b * NQ + n0 + row1) * DD + 4 * (lrow ^ (row1 & 15));

    // ---- B staging source: wave wid stages mt=wid, segs sl=0..3 ----
    const unsigned short* bsrc =
        Pf + (((size_t)(b * 4 + wid)) * 64) * 512 + (size_t)lane * 8;

    const float sc = scale[0] * (1.0f / (float)DD);
    float pt[4];
    #pragma unroll
    for (int mt = 0; mt < 4; ++mt)
        pt[mt] = Pterm[b * MP + 16 * mt + lrow];

    f32x4 acc[2][4];
    #pragma unroll
    for (int nt = 0; nt < 2; ++nt)
        #pragma unroll
        for (int mt = 0; mt < 4; ++mt)
            acc[nt][mt] = (f32x4){0.f, 0.f, 0.f, 0.f};

    // ---- stage chunk 0 into buf 0 ----
    {
        async_ld16(qsrc0, &Qsh[0][(wid * 2 + 0) * 256]);
        async_ld16(qsrc1, &Qsh[0][(wid * 2 + 1) * 256]);
        #pragma unroll
        for (int sl = 0; sl < 4; ++sl)
            async_ld16(bsrc + (size_t)sl * 512, &Bsh[0][(wid * 4 + sl) * 512]);
    }

    for (int kt = 0; kt < KT; ++kt) {
        const int c = kt & 1;
        __syncthreads();   // drains stage(kt) [implicit vmcnt(0)]; WAR vs compute(kt-1)

        // ---- issue async stage of chunk kt+1; overlaps compute below ----
        if (kt + 1 < KT) {
            const int nc = c ^ 1;
            async_ld16(qsrc0 + (size_t)(kt + 1) * BK, &Qsh[nc][(wid * 2 + 0) * 256]);
            async_ld16(qsrc1 + (size_t)(kt + 1) * BK, &Qsh[nc][(wid * 2 + 1) * 256]);
            #pragma unroll
            for (int sl = 0; sl < 4; ++sl)
                async_ld16(bsrc + (size_t)(4 * (kt + 1) + sl) * 512,
                           &Bsh[nc][(wid * 4 + sl) * 512]);
        }

        // ---- compute chunk kt: 4 sl-steps x (2 A-frags, 4 m-tiles) ----
        #pragma unroll
        for (int sl = 0; sl < 4; ++sl) {
            bf16x8 afr[2];
            #pragma unroll
            for (int nt = 0; nt < 2; ++nt) {
                const int row = 16 * nt + lrow;
                const int dgx = (4 * sl + quad) ^ lrow;
                const float4 q = *(const float4*)&Qsh[c][(row * 16 + dgx) * 4];
                union { uint4 u; bf16x8 b; } cv;
                cv.u.x = pk2(q.x * q.x, q.x);
                cv.u.y = pk2(q.y * q.y, q.y);
                cv.u.z = pk2(q.z * q.z, q.z);
                cv.u.w = pk2(q.w * q.w, q.w);
                afr[nt] = cv.b;
            }
            #pragma unroll
            for (int mt = 0; mt < 4; ++mt) {
                const bf16x8 bb =
                    *(const bf16x8*)&Bsh[c][(mt * 4 + sl) * 512 + lane * 8];
                acc[0][mt] = __builtin_amdgcn_mfma_f32_16x16x32_bf16(afr[0], bb, acc[0][mt], 0, 0, 0);
                acc[1][mt] = __builtin_amdgcn_mfma_f32_16x16x32_bf16(afr[1], bb, acc[1][mt], 0, 0, 0);
            }
        }
    }

    // ---- epilogue: n = n0 + 16*nt + quad*4 + r, m = 16*mt + lrow ----
    #pragma unroll
    for (int nt = 0; nt < 2; ++nt) {
        #pragma unroll
        for (int mt = 0; mt < 4; ++mt) {
            const size_t ob =
                ((size_t)b * NQ + (size_t)(n0 + 16 * nt + quad * 4)) * MP + 16 * mt + lrow;
            #pragma unroll
            for (int r = 0; r < 4; ++r)
                out[ob + (size_t)r * MP] = (acc[nt][mt][r] + pt[mt]) * sc;
        }
    }
}

extern "C" void kernel_launch(void* const* d_in, const int* in_sizes, int n_in,
                              void* d_out, int out_size, void* d_ws, size_t ws_size,
                              hipStream_t stream) {
    (void)in_sizes; (void)n_in; (void)ws_size; (void)out_size;
    const float* proto = (const float*)d_in[0];
    const float* mask  = (const float*)d_in[1];
    const float* query = (const float*)d_in[2];
    const float* scale = (const float*)d_in[5];
    float* out = (float*)d_out;

    unsigned short* Pf = (unsigned short*)d_ws;                           // 2 MiB
    float* Pterm = (float*)((char*)d_ws + (size_t)BSZ * MP * K2ALL * 2);  // +2 KiB

    pack_kernel<<<dim3(BSZ * MP), dim3(256), 0, stream>>>(proto, mask, Pf, Pterm);
    proto_main_kernel<<<dim3(BSZ * NTILES), dim3(256), 0, stream>>>(
        query, Pf, Pterm, scale, out);
}